// Round 9
// baseline (174.551 us; speedup 1.0000x reference)
//
#include <hip/hip_runtime.h>
#include <hip/hip_bf16.h>

typedef __attribute__((ext_vector_type(4))) float f32x4;
typedef __attribute__((ext_vector_type(8))) short s16x8;

#define W2P_BYTES   8388608ull                 // 64*256*256 bf16
#define SLAB_FLOATS 1048576ull                 // 4096*256
#define WS_NEEDED   (W2P_BYTES + 7ull * SLAB_FLOATS * 4ull)

// ---------------------------------------------------------------------------
// k0: pack g_fc2_w (64,256,256) fp32 -> bf16 MFMA fragments, 1KB contiguous
// per fragment.  frag f = (n*8+ks)*16 + ct  (ct = col/16):
//   lane l, elem j = g2w[n][ks*32 + (l>>4)*8 + j][ct*16 + (l&15)]
// ---------------------------------------------------------------------------
__global__ __launch_bounds__(256) void k0_pack(const float* __restrict__ w2,
                                               ushort* __restrict__ out) {
  __shared__ float tile[32][257];
  const int n = blockIdx.x >> 3, ks = blockIdx.x & 7;
  const float* src = w2 + ((size_t)n * 256 + ks * 32) * 256;
  for (int i = threadIdx.x; i < 8192; i += 256)
    tile[i >> 8][i & 255] = src[i];
  __syncthreads();
#pragma unroll
  for (int q = 0; q < 4; ++q) {
    int chunk = q * 256 + threadIdx.x;
    int ct = chunk >> 6, l = chunk & 63;
    int g = l >> 4, cl = l & 15;
    s16x8 pk;
#pragma unroll
    for (int j = 0; j < 8; ++j) {
      __hip_bfloat16 h = __float2bfloat16(tile[g * 8 + j][ct * 16 + cl]);
      pk[j] = *reinterpret_cast<short*>(&h);
    }
    *reinterpret_cast<s16x8*>(out + ((size_t)(n * 8 + ks) * 1024 + chunk) * 8) = pk;
  }
}

// ---------------------------------------------------------------------------
// k1: f-path -> sparse_w (4096,64).  8 rows per block, 256 threads, grid 512.
// ---------------------------------------------------------------------------
__global__ __launch_bounds__(256) void k1_select(
    const float* __restrict__ x,
    const float* __restrict__ w1, const float* __restrict__ b1,
    const float* __restrict__ w2, const float* __restrict__ b2,
    const float* __restrict__ wsk, const float* __restrict__ bsk,
    const float* __restrict__ wg, const float* __restrict__ bg,
    const float* __restrict__ lng, const float* __restrict__ lnb,
    float* __restrict__ spw) {
  __shared__ float xs[8][64];
  __shared__ float t1[8][256];
  __shared__ float wvv[8][64];
  const int t = threadIdx.x;
  const int b0 = blockIdx.x * 8;
  if (t < 128) {
    const f32x4* xin = reinterpret_cast<const f32x4*>(x + (size_t)b0 * 64);
    reinterpret_cast<f32x4*>(&xs[0][0])[t] = xin[t];
  }
  __syncthreads();
  {  // t1[r][h] = elu(x @ f_fc1_w + b1), thread t = h
    float acc[8];
    float bias = b1[t];
#pragma unroll
    for (int r = 0; r < 8; ++r) acc[r] = bias;
    for (int n = 0; n < 64; ++n) {
      float w = w1[n * 256 + t];
#pragma unroll
      for (int r = 0; r < 8; ++r) acc[r] = fmaf(xs[r][n], w, acc[r]);
    }
#pragma unroll
    for (int r = 0; r < 8; ++r) {
      float z = acc[r];
      t1[r][t] = fmaxf(z, 0.f) + (__expf(fminf(z, 0.f)) - 1.f);
    }
  }
  __syncthreads();
  {  // h2 / skip / gate, thread = (nn = t&63, rg = t>>6), rows rg, rg+4
    const int nn = t & 63, rg = t >> 6;
    float a2[2], as_[2], ag[2];
    float bb2 = b2[nn], bbs = bsk[nn], bbg = bg[nn];
#pragma unroll
    for (int i = 0; i < 2; ++i) { a2[i] = bb2; as_[i] = bbs; ag[i] = bbg; }
    for (int h = 0; h < 256; ++h) {
      float w = w2[h * 64 + nn];
#pragma unroll
      for (int i = 0; i < 2; ++i) a2[i] = fmaf(t1[rg + 4 * i][h], w, a2[i]);
    }
    for (int m = 0; m < 64; ++m) {
      float ws_ = wsk[m * 64 + nn], wg_ = wg[m * 64 + nn];
#pragma unroll
      for (int i = 0; i < 2; ++i) {
        float xv = xs[rg + 4 * i][m];
        as_[i] = fmaf(xv, ws_, as_[i]);
        ag[i]  = fmaf(xv, wg_, ag[i]);
      }
    }
#pragma unroll
    for (int i = 0; i < 2; ++i) {
      float gt = __fdividef(1.f, 1.f + __expf(-ag[i]));
      wvv[rg + 4 * i][nn] = fmaf(gt, a2[i] - as_[i], as_[i]);
    }
  }
  __syncthreads();
  {  // LN over 64 + softmax over 64, wave handles 2 rows
    const int lane = t & 63, wid = t >> 6;
    float gl = lng[lane], bl = lnb[lane];
#pragma unroll
    for (int rr = 0; rr < 2; ++rr) {
      int r = wid * 2 + rr;
      float v = wvv[r][lane];
      float s = v;
      for (int m = 1; m < 64; m <<= 1) s += __shfl_xor(s, m);
      float mu = s * (1.f / 64.f);
      float d = v - mu;
      float q = d * d;
      for (int m = 1; m < 64; m <<= 1) q += __shfl_xor(q, m);
      float wn = d * rsqrtf(q * (1.f / 64.f) + 1e-5f) * gl + bl;
      float mx = wn;
      for (int m = 1; m < 64; m <<= 1) mx = fmaxf(mx, __shfl_xor(mx, m));
      float e = __expf(wn - mx);
      float se = e;
      for (int m = 1; m < 64; m <<= 1) se += __shfl_xor(se, m);
      spw[(size_t)(b0 + r) * 64 + lane] = __fdividef(e, se);
    }
  }
}

// ---------------------------------------------------------------------------
// k2: fused einsum + gate/skip + LN(H) + weighted accumulate.
// grid 1024: bid = btile*8 + nchunk (nchunk = bid&7 -> XCD-pinned weights).
// 512 threads / 8 waves, 32 rows x 8 n, 2 blocks/CU, grid = 2 full rounds.
// ONE barrier per ni:
//   barrier -> pass2(ni-1) -> ks-loop(ni) -> ep1(ni)+sums atomics
//           -> A-gen(ni+1)   (A-gen drains the atomics before the barrier)
// Ab double-buffered (A-gen(ni+1) vs ks-loop(ni)); sums 3-buffer rotation
// (zero buf (ni+1)%3 each iter -- its readers finished >=1 barrier ago).
// W-frag prefetch depth 4 (wbuf[ks&3], 8%4==0 -> uniform across n boundary).
// ---------------------------------------------------------------------------
template <bool ATOMIC>
__global__ __launch_bounds__(512, 4) void k2_main(
    const float* __restrict__ x,
    const ushort* __restrict__ w2p,
    const float* __restrict__ fc1w, const float* __restrict__ fc1b,
    const float* __restrict__ fc2b,
    const float* __restrict__ skw, const float* __restrict__ skb,
    const float* __restrict__ gww, const float* __restrict__ gwb,
    const float* __restrict__ lng, const float* __restrict__ lnb,
    const float* __restrict__ spw,
    float* __restrict__ comb, float* __restrict__ slabs) {
  __shared__ __align__(16) char Ab[2][16384];  // act tiles 32x256 bf16, swizzled
  __shared__ float xs[32][9];
  __shared__ float ss[32][9];
  __shared__ float sums[3][32][2];

  const int bid = blockIdx.x;
  const int nch = bid & 7;
  const int b0  = (bid >> 3) * 32;
  const int t = threadIdx.x;
  const int lane = t & 63;
  const int w = t >> 6;          // 0..7 (32-col band)
  const int g = lane >> 4;
  const int cl = lane & 15;
  const int n0 = nch * 8;

  if (t < 256) {
    int r = t >> 3, j = t & 7;
    xs[r][j] = x[(size_t)(b0 + r) * 64 + nch * 8 + j];
    ss[r][j] = spw[(size_t)(b0 + r) * 64 + nch * 8 + j];
  }
  if (t < 192) (&sums[0][0][0])[t] = 0.f;

  f32x4 comb_acc[2][2];
  f32x4 acc[2][2];               // live across the barrier into pass2
#pragma unroll
  for (int a = 0; a < 2; ++a)
#pragma unroll
    for (int b = 0; b < 2; ++b) comb_acc[a][b] = (f32x4){0.f, 0.f, 0.f, 0.f};

  const s16x8* wf = reinterpret_cast<const s16x8*>(w2p);
#define BFRAG(nn, kk, ct) \
  (wf + (((size_t)((nn) * 8 + (kk)) * 16 + w * 2 + (ct)) * 64 + lane))

  // A-gen: act[r][k] = elu(x[b0+r][nn]*fc1w[nn][k] + fc1b[nn][k]) -> abuf
  auto AGEN = [&](int nn, char* abuf) {
    const int kc = t & 31;
    const int rb = t >> 5;       // 0..15
    const int nloc = nn - n0;
    const float* w1p = fc1w + nn * 256 + kc * 8;
    const float* b1p = fc1b + nn * 256 + kc * 8;
    f32x4 wlo = *reinterpret_cast<const f32x4*>(w1p);
    f32x4 whi = *reinterpret_cast<const f32x4*>(w1p + 4);
    f32x4 blo = *reinterpret_cast<const f32x4*>(b1p);
    f32x4 bhi = *reinterpret_cast<const f32x4*>(b1p + 4);
#pragma unroll
    for (int i = 0; i < 2; ++i) {
      int r = rb + 16 * i;
      float xv = xs[r][nloc];
      s16x8 pk;
#pragma unroll
      for (int j = 0; j < 4; ++j) {
        float z0 = fmaf(xv, wlo[j], blo[j]);
        float z1 = fmaf(xv, whi[j], bhi[j]);
        float e0 = fmaxf(z0, 0.f) + (__expf(fminf(z0, 0.f)) - 1.f);
        float e1 = fmaxf(z1, 0.f) + (__expf(fminf(z1, 0.f)) - 1.f);
        __hip_bfloat16 h0 = __float2bfloat16(e0);
        __hip_bfloat16 h1 = __float2bfloat16(e1);
        pk[j]     = *reinterpret_cast<short*>(&h0);
        pk[j + 4] = *reinterpret_cast<short*>(&h1);
      }
      *reinterpret_cast<s16x8*>(abuf + r * 512 + ((kc << 4) ^ ((r & 7) << 4))) = pk;
    }
  };

  // pass2 for n index pni (0..7): normalize + softmax-weighted accumulate
  auto PASS2 = [&](int pni) {
    const int pn = n0 + pni;
    const float* sb = &sums[pni % 3][0][0];
    float rsv[2], mrs[2], svv[2];
#pragma unroll
    for (int rt = 0; rt < 2; ++rt) {
      int row = rt * 16 + cl;
      float s0 = sb[row * 2], s1 = sb[row * 2 + 1];
      float mu = s0 * (1.f / 256.f);
      float rs = rsqrtf(fmaxf(s1 * (1.f / 256.f) - mu * mu, 0.f) + 1e-5f);
      rsv[rt] = rs;
      mrs[rt] = -mu * rs;
      svv[rt] = ss[row][pni];
    }
#pragma unroll
    for (int ct = 0; ct < 2; ++ct) {
      const int c4 = pn * 256 + (w * 2 + ct) * 16 + g * 4;
      f32x4 lg4 = *reinterpret_cast<const f32x4*>(lng + c4);
      f32x4 lb4 = *reinterpret_cast<const f32x4*>(lnb + c4);
#pragma unroll
      for (int rt = 0; rt < 2; ++rt) {
#pragma unroll
        for (int j = 0; j < 4; ++j) {
          float tnorm = fmaf(acc[ct][rt][j], rsv[rt], mrs[rt]);
          float emb = fmaf(tnorm, lg4[j], lb4[j]);
          comb_acc[ct][rt][j] = fmaf(svv[rt], emb, comb_acc[ct][rt][j]);
        }
      }
    }
  };

  __syncthreads();               // xs/ss/sums-zero visible

  // prologue: W frags ks=0..3 of n0 + act(n0) into Ab[0]
  s16x8 wbuf[4][2];
#pragma unroll
  for (int s = 0; s < 4; ++s) {
    wbuf[s][0] = *BFRAG(n0, s, 0);
    wbuf[s][1] = *BFRAG(n0, s, 1);
  }
  AGEN(n0, Ab[0]);

#pragma unroll 1
  for (int ni = 0; ni < 8; ++ni) {
    const int n = n0 + ni;
    __syncthreads();             // Ab[ni&1] ready; sums[(ni-1)%3] visible

    if (t < 64) (&sums[(ni + 1) % 3][0][0])[t] = 0.f;  // rotate-zero
    if (ni > 0) PASS2(ni - 1);

    // ---- K-loop: 8 ks, MFMA from Ab[ni&1] x wbuf, prefetch 4 ahead ----
#pragma unroll
    for (int a = 0; a < 2; ++a)
#pragma unroll
      for (int b = 0; b < 2; ++b) acc[a][b] = (f32x4){0.f, 0.f, 0.f, 0.f};

    const char* abase = Ab[ni & 1];
#pragma unroll
    for (int ks = 0; ks < 8; ++ks) {
      s16x8 af[2];
#pragma unroll
      for (int rt = 0; rt < 2; ++rt) {
        int row = rt * 16 + cl;
        af[rt] = *reinterpret_cast<const s16x8*>(
            abase + row * 512 + (((ks * 4 + g) << 4) ^ ((row & 7) << 4)));
      }
#pragma unroll
      for (int ct = 0; ct < 2; ++ct)
#pragma unroll
        for (int rt = 0; rt < 2; ++rt)
          acc[ct][rt] = __builtin_amdgcn_mfma_f32_16x16x32_bf16(
              wbuf[ks & 3][ct], af[rt], acc[ct][rt], 0, 0, 0);
      if (ni < 7 || ks < 4) {    // prefetch global step ks+4 (crosses into n+1)
        const int nn2 = n + ((ks + 4) >> 3);
        const int kk2 = (ks + 4) & 7;
        wbuf[ks & 3][0] = *BFRAG(nn2, kk2, 0);
        wbuf[ks & 3][1] = *BFRAG(nn2, kk2, 1);
      }
    }

    // ---- ep1: gate mix + lane-local row stats -> sums[ni%3] ----
    {
      float xr[2], rsum[2], rsq[2];
#pragma unroll
      for (int rt = 0; rt < 2; ++rt) {
        xr[rt] = xs[rt * 16 + cl][ni];
        rsum[rt] = 0.f;
        rsq[rt] = 0.f;
      }
#pragma unroll
      for (int ct = 0; ct < 2; ++ct) {
        const int c4 = n * 256 + (w * 2 + ct) * 16 + g * 4;
        f32x4 f2b4 = *reinterpret_cast<const f32x4*>(fc2b + c4);
        f32x4 sw4  = *reinterpret_cast<const f32x4*>(skw + c4);
        f32x4 sb4  = *reinterpret_cast<const f32x4*>(skb + c4);
        f32x4 gw4  = *reinterpret_cast<const f32x4*>(gww + c4);
        f32x4 gb4  = *reinterpret_cast<const f32x4*>(gwb + c4);
#pragma unroll
        for (int rt = 0; rt < 2; ++rt) {
#pragma unroll
          for (int j = 0; j < 4; ++j) {
            float hv = acc[ct][rt][j] + f2b4[j];
            float sk = fmaf(xr[rt], sw4[j], sb4[j]);
            float gv = __fdividef(1.f, 1.f + __expf(-fmaf(xr[rt], gw4[j], gb4[j])));
            float p = fmaf(gv, hv - sk, sk);
            acc[ct][rt][j] = p;
            rsum[rt] += p;
            rsq[rt] = fmaf(p, p, rsq[rt]);
          }
        }
      }
#pragma unroll
      for (int rt = 0; rt < 2; ++rt) {
        rsum[rt] += __shfl_xor(rsum[rt], 16);
        rsum[rt] += __shfl_xor(rsum[rt], 32);
        rsq[rt]  += __shfl_xor(rsq[rt], 16);
        rsq[rt]  += __shfl_xor(rsq[rt], 32);
      }
      if (g == 0) {
        float* sb = &sums[ni % 3][0][0];
#pragma unroll
        for (int rt = 0; rt < 2; ++rt) {
          atomicAdd(&sb[(rt * 16 + cl) * 2 + 0], rsum[rt]);
          atomicAdd(&sb[(rt * 16 + cl) * 2 + 1], rsq[rt]);
        }
      }
    }

    // ---- A-gen for ni+1 (drains the atomics before the next barrier) ----
    if (ni < 7) AGEN(n + 1, Ab[(ni + 1) & 1]);
  }

  __syncthreads();               // final sums visible
  PASS2(7);
#undef BFRAG

  float* outp;
  if (ATOMIC) outp = comb;
  else outp = (nch == 0) ? comb : slabs + (size_t)(nch - 1) * SLAB_FLOATS;
#pragma unroll
  for (int ct = 0; ct < 2; ++ct)
#pragma unroll
    for (int rt = 0; rt < 2; ++rt) {
      size_t idx = (size_t)(b0 + rt * 16 + cl) * 256 + (w * 2 + ct) * 16 + g * 4;
      if (ATOMIC) {
#pragma unroll
        for (int j = 0; j < 4; ++j)
          atomicAdd(&outp[idx + j], comb_acc[ct][rt][j]);
      } else {
        *reinterpret_cast<f32x4*>(outp + idx) = comb_acc[ct][rt];
      }
    }
}

// ---------------------------------------------------------------------------
// k3: comb += sum of the 7 partial slabs.  grid 1024 x 256, f32x4 per thread.
// ---------------------------------------------------------------------------
__global__ __launch_bounds__(256) void k3_reduce(float* __restrict__ comb,
                                                 const float* __restrict__ slabs) {
  size_t i = (size_t)blockIdx.x * 256 + threadIdx.x;   // f32x4 index
  f32x4 v = reinterpret_cast<const f32x4*>(comb)[i];
#pragma unroll
  for (int s = 0; s < 7; ++s)
    v += reinterpret_cast<const f32x4*>(slabs)[s * (SLAB_FLOATS / 4) + i];
  reinterpret_cast<f32x4*>(comb)[i] = v;
}

// ---------------------------------------------------------------------------
extern "C" void kernel_launch(void* const* d_in, const int* in_sizes, int n_in,
                              void* d_out, int out_size, void* d_ws, size_t ws_size,
                              hipStream_t stream) {
  const float* x   = (const float*)d_in[0];
  const float* f1w = (const float*)d_in[1];
  const float* f1b = (const float*)d_in[2];
  const float* f2w = (const float*)d_in[3];
  const float* f2b = (const float*)d_in[4];
  const float* fsw = (const float*)d_in[5];
  const float* fsb = (const float*)d_in[6];
  const float* fgw = (const float*)d_in[7];
  const float* fgb = (const float*)d_in[8];
  const float* flg = (const float*)d_in[9];
  const float* flb = (const float*)d_in[10];
  const float* g1w = (const float*)d_in[11];
  const float* g1b = (const float*)d_in[12];
  const float* g2w = (const float*)d_in[13];
  const float* g2b = (const float*)d_in[14];
  const float* gsw = (const float*)d_in[15];
  const float* gsb = (const float*)d_in[16];
  const float* ggw = (const float*)d_in[17];
  const float* ggb = (const float*)d_in[18];
  const float* glg = (const float*)d_in[19];
  const float* glb = (const float*)d_in[20];

  float* out  = (float*)d_out;
  float* comb = out;                          // (4096,256)
  float* spw  = out + (size_t)4096 * 256;     // (4096,64)
  ushort* w2p = (ushort*)d_ws;                // 8.4 MB packed bf16 W-frags
  float* slabs = (float*)((char*)d_ws + W2P_BYTES);  // 7 x 4 MB partials

  k0_pack<<<512, 256, 0, stream>>>(g2w, w2p);
  k1_select<<<512, 256, 0, stream>>>(x, f1w, f1b, f2w, f2b, fsw, fsb,
                                     fgw, fgb, flg, flb, spw);
  if (ws_size >= WS_NEEDED) {
    k2_main<false><<<1024, 512, 0, stream>>>(x, w2p, g1w, g1b, g2b, gsw, gsb,
                                             ggw, ggb, glg, glb, spw, comb, slabs);
    k3_reduce<<<1024, 256, 0, stream>>>(comb, slabs);
  } else {
    hipMemsetAsync(comb, 0, (size_t)4096 * 256 * sizeof(float), stream);
    k2_main<true><<<1024, 512, 0, stream>>>(x, w2p, g1w, g1b, g2b, gsw, gsb,
                                            ggw, ggb, glg, glb, spw, comb, slabs);
  }
}

// Round 10
// 136.436 us; speedup vs baseline: 1.2794x; 1.2794x over previous
//
#include <hip/hip_runtime.h>
#include <hip/hip_bf16.h>

typedef __attribute__((ext_vector_type(4))) float f32x4;
typedef __attribute__((ext_vector_type(8))) short s16x8;

#define W2P_BYTES   8388608ull                 // 64*256*256 bf16
#define SLAB_FLOATS 1048576ull                 // 4096*256
#define WS_NEEDED   (W2P_BYTES + 7ull * SLAB_FLOATS * 4ull)

// ---------------------------------------------------------------------------
// k0: pack g_fc2_w (64,256,256) fp32 -> bf16 MFMA fragments, 1KB contiguous
// per fragment.  frag f = (n*8+ks)*16 + ct  (ct = col/16):
//   lane l, elem j = g2w[n][ks*32 + (l>>4)*8 + j][ct*16 + (l&15)]
// ---------------------------------------------------------------------------
__global__ __launch_bounds__(256) void k0_pack(const float* __restrict__ w2,
                                               ushort* __restrict__ out) {
  __shared__ float tile[32][257];
  const int n = blockIdx.x >> 3, ks = blockIdx.x & 7;
  const float* src = w2 + ((size_t)n * 256 + ks * 32) * 256;
  for (int i = threadIdx.x; i < 8192; i += 256)
    tile[i >> 8][i & 255] = src[i];
  __syncthreads();
#pragma unroll
  for (int q = 0; q < 4; ++q) {
    int chunk = q * 256 + threadIdx.x;
    int ct = chunk >> 6, l = chunk & 63;
    int g = l >> 4, cl = l & 15;
    s16x8 pk;
#pragma unroll
    for (int j = 0; j < 8; ++j) {
      __hip_bfloat16 h = __float2bfloat16(tile[g * 8 + j][ct * 16 + cl]);
      pk[j] = *reinterpret_cast<short*>(&h);
    }
    *reinterpret_cast<s16x8*>(out + ((size_t)(n * 8 + ks) * 1024 + chunk) * 8) = pk;
  }
}

// ---------------------------------------------------------------------------
// k1: f-path -> sparse_w (4096,64).  8 rows per block, 256 threads, grid 512.
// ---------------------------------------------------------------------------
__global__ __launch_bounds__(256) void k1_select(
    const float* __restrict__ x,
    const float* __restrict__ w1, const float* __restrict__ b1,
    const float* __restrict__ w2, const float* __restrict__ b2,
    const float* __restrict__ wsk, const float* __restrict__ bsk,
    const float* __restrict__ wg, const float* __restrict__ bg,
    const float* __restrict__ lng, const float* __restrict__ lnb,
    float* __restrict__ spw) {
  __shared__ float xs[8][64];
  __shared__ float t1[8][256];
  __shared__ float wvv[8][64];
  const int t = threadIdx.x;
  const int b0 = blockIdx.x * 8;
  if (t < 128) {
    const f32x4* xin = reinterpret_cast<const f32x4*>(x + (size_t)b0 * 64);
    reinterpret_cast<f32x4*>(&xs[0][0])[t] = xin[t];
  }
  __syncthreads();
  {  // t1[r][h] = elu(x @ f_fc1_w + b1), thread t = h
    float acc[8];
    float bias = b1[t];
#pragma unroll
    for (int r = 0; r < 8; ++r) acc[r] = bias;
    for (int n = 0; n < 64; ++n) {
      float w = w1[n * 256 + t];
#pragma unroll
      for (int r = 0; r < 8; ++r) acc[r] = fmaf(xs[r][n], w, acc[r]);
    }
#pragma unroll
    for (int r = 0; r < 8; ++r) {
      float z = acc[r];
      t1[r][t] = fmaxf(z, 0.f) + (__expf(fminf(z, 0.f)) - 1.f);
    }
  }
  __syncthreads();
  {  // h2 / skip / gate, thread = (nn = t&63, rg = t>>6), rows rg, rg+4
    const int nn = t & 63, rg = t >> 6;
    float a2[2], as_[2], ag[2];
    float bb2 = b2[nn], bbs = bsk[nn], bbg = bg[nn];
#pragma unroll
    for (int i = 0; i < 2; ++i) { a2[i] = bb2; as_[i] = bbs; ag[i] = bbg; }
    for (int h = 0; h < 256; ++h) {
      float w = w2[h * 64 + nn];
#pragma unroll
      for (int i = 0; i < 2; ++i) a2[i] = fmaf(t1[rg + 4 * i][h], w, a2[i]);
    }
    for (int m = 0; m < 64; ++m) {
      float ws_ = wsk[m * 64 + nn], wg_ = wg[m * 64 + nn];
#pragma unroll
      for (int i = 0; i < 2; ++i) {
        float xv = xs[rg + 4 * i][m];
        as_[i] = fmaf(xv, ws_, as_[i]);
        ag[i]  = fmaf(xv, wg_, ag[i]);
      }
    }
#pragma unroll
    for (int i = 0; i < 2; ++i) {
      float gt = __fdividef(1.f, 1.f + __expf(-ag[i]));
      wvv[rg + 4 * i][nn] = fmaf(gt, a2[i] - as_[i], as_[i]);
    }
  }
  __syncthreads();
  {  // LN over 64 + softmax over 64, wave handles 2 rows
    const int lane = t & 63, wid = t >> 6;
    float gl = lng[lane], bl = lnb[lane];
#pragma unroll
    for (int rr = 0; rr < 2; ++rr) {
      int r = wid * 2 + rr;
      float v = wvv[r][lane];
      float s = v;
      for (int m = 1; m < 64; m <<= 1) s += __shfl_xor(s, m);
      float mu = s * (1.f / 64.f);
      float d = v - mu;
      float q = d * d;
      for (int m = 1; m < 64; m <<= 1) q += __shfl_xor(q, m);
      float wn = d * rsqrtf(q * (1.f / 64.f) + 1e-5f) * gl + bl;
      float mx = wn;
      for (int m = 1; m < 64; m <<= 1) mx = fmaxf(mx, __shfl_xor(mx, m));
      float e = __expf(wn - mx);
      float se = e;
      for (int m = 1; m < 64; m <<= 1) se += __shfl_xor(se, m);
      spw[(size_t)(b0 + r) * 64 + lane] = __fdividef(e, se);
    }
  }
}

// ---------------------------------------------------------------------------
// k2: fused einsum + gate/skip + LN(H) + weighted accumulate.
// R8 structure (133us, clean) + zero-register LDS param staging:
// the 7 per-n param rows (fc2b,skw,skb,gww,gwb,lng,lnb -> 7KB) are staged
// one iteration ahead via global_load_lds (wave w<7 stages array w, one
// width-16 instruction), double-buffered.  Issue after B1(ni) (ping-pong
// buffer dead: all waves past pass2(ni-1)); drained by B2(ni)'s vmcnt(0);
// read in ep1/pass2(ni+1) as ds_read_b128 (~12cy) instead of L2 (~200cy).
// grid 1024: bid = btile*8 + nchunk; 512 thr / 8 waves; 2 blocks/CU; no tail.
// ---------------------------------------------------------------------------
template <bool ATOMIC>
__global__ __launch_bounds__(512, 4) void k2_main(
    const float* __restrict__ x,
    const ushort* __restrict__ w2p,
    const float* __restrict__ fc1w, const float* __restrict__ fc1b,
    const float* __restrict__ fc2b,
    const float* __restrict__ skw, const float* __restrict__ skb,
    const float* __restrict__ gww, const float* __restrict__ gwb,
    const float* __restrict__ lng, const float* __restrict__ lnb,
    const float* __restrict__ spw,
    float* __restrict__ comb, float* __restrict__ slabs) {
  __shared__ __align__(16) char Ab[16384];      // act tile 32x256 bf16, swizzled
  __shared__ __align__(16) float pbuf[2][1792]; // 7 param rows x 256, dbuf
  __shared__ float xs[32][9];
  __shared__ float ss[32][9];
  __shared__ float sums[2][32][2];

  const int bid = blockIdx.x;
  const int nch = bid & 7;
  const int b0  = (bid >> 3) * 32;
  const int t = threadIdx.x;
  const int lane = t & 63;
  const int w = t >> 6;          // 0..7 (32-col band)
  const int g = lane >> 4;
  const int cl = lane & 15;
  const int n0 = nch * 8;

  if (t < 256) {
    int r = t >> 3, j = t & 7;
    xs[r][j] = x[(size_t)(b0 + r) * 64 + nch * 8 + j];
    ss[r][j] = spw[(size_t)(b0 + r) * 64 + nch * 8 + j];
  }
  if (t < 64) (&sums[0][0][0])[t] = 0.f;

  // stage params(nn) -> pbuf[buf]: wave w<7 stages its array, 1 inst/wave
  auto STAGE = [&](int nn, int buf) {
    if (w < 7) {
      const float* ps;
      switch (w) {
        case 0: ps = fc2b; break;
        case 1: ps = skw;  break;
        case 2: ps = skb;  break;
        case 3: ps = gww;  break;
        case 4: ps = gwb;  break;
        case 5: ps = lng;  break;
        default: ps = lnb; break;
      }
      __builtin_amdgcn_global_load_lds(
          (const __attribute__((address_space(1))) unsigned int*)(ps + nn * 256 + lane * 4),
          (__attribute__((address_space(3))) unsigned int*)&pbuf[buf][w * 256],
          16, 0, 0);
    }
  };

  f32x4 comb_acc[2][2];
#pragma unroll
  for (int a = 0; a < 2; ++a)
#pragma unroll
    for (int b = 0; b < 2; ++b) comb_acc[a][b] = (f32x4){0.f, 0.f, 0.f, 0.f};

  const s16x8* wf = reinterpret_cast<const s16x8*>(w2p);
#define BFRAG(nn, kk, ct) \
  (wf + (((size_t)((nn) * 8 + (kk)) * 16 + w * 2 + (ct)) * 64 + lane))

  STAGE(n0, 0);                  // params(n0); drained by the barrier below
  __syncthreads();

  for (int ni = 0; ni < 8; ++ni) {
    const int n = n0 + ni;
    // ---- issue W prefetch for ks=0,1 of THIS n (covered by A-gen) ----
    s16x8 bfa[2], bfb[2];
#pragma unroll
    for (int ct = 0; ct < 2; ++ct) {
      bfa[ct] = *BFRAG(n, 0, ct);
      bfb[ct] = *BFRAG(n, 1, ct);
    }

    // ---- A-gen: act[r][k] = elu(x[b0+r][n]*fc1w[n][k] + fc1b[n][k]) ----
    {
      const int kc = t & 31;
      const int rb = t >> 5;     // 0..15
      const float* w1p = fc1w + n * 256 + kc * 8;
      const float* b1p = fc1b + n * 256 + kc * 8;
      f32x4 wlo = *reinterpret_cast<const f32x4*>(w1p);
      f32x4 whi = *reinterpret_cast<const f32x4*>(w1p + 4);
      f32x4 blo = *reinterpret_cast<const f32x4*>(b1p);
      f32x4 bhi = *reinterpret_cast<const f32x4*>(b1p + 4);
#pragma unroll
      for (int i = 0; i < 2; ++i) {
        int r = rb + 16 * i;
        float xv = xs[r][ni];
        s16x8 pk;
#pragma unroll
        for (int j = 0; j < 4; ++j) {
          float z0 = fmaf(xv, wlo[j], blo[j]);
          float z1 = fmaf(xv, whi[j], bhi[j]);
          float e0 = fmaxf(z0, 0.f) + (__expf(fminf(z0, 0.f)) - 1.f);
          float e1 = fmaxf(z1, 0.f) + (__expf(fminf(z1, 0.f)) - 1.f);
          __hip_bfloat16 h0 = __float2bfloat16(e0);
          __hip_bfloat16 h1 = __float2bfloat16(e1);
          pk[j]     = *reinterpret_cast<short*>(&h0);
          pk[j + 4] = *reinterpret_cast<short*>(&h1);
        }
        *reinterpret_cast<s16x8*>(Ab + r * 512 + ((kc << 4) ^ ((r & 7) << 4))) = pk;
      }
    }
    __syncthreads();   // B1: Ab ready; all waves past previous pass-2

    // stage params(n+1) into the other buffer (safe: its readers done)
    if (ni < 7) STAGE(n + 1, (ni + 1) & 1);

    f32x4 acc[2][2];   // [ct][rt]
#pragma unroll
    for (int a = 0; a < 2; ++a)
#pragma unroll
      for (int b = 0; b < 2; ++b) acc[a][b] = (f32x4){0.f, 0.f, 0.f, 0.f};

#pragma unroll
    for (int ks = 0; ks < 8; ++ks) {
      s16x8* cur = (ks & 1) ? bfb : bfa;
      s16x8 af[2];
#pragma unroll
      for (int rt = 0; rt < 2; ++rt) {
        int row = rt * 16 + cl;
        af[rt] = *reinterpret_cast<const s16x8*>(
            Ab + row * 512 + (((ks * 4 + g) << 4) ^ ((row & 7) << 4)));
      }
#pragma unroll
      for (int ct = 0; ct < 2; ++ct)
#pragma unroll
        for (int rt = 0; rt < 2; ++rt)
          acc[ct][rt] = __builtin_amdgcn_mfma_f32_16x16x32_bf16(
              cur[ct], af[rt], acc[ct][rt], 0, 0, 0);
      if (ks < 6) {
#pragma unroll
        for (int ct = 0; ct < 2; ++ct) cur[ct] = *BFRAG(n, ks + 2, ct);
      }
    }

    // ---- epilogue pass 1: gate mix + lane-local row stats ----
    const int par = ni & 1;
    const float* pb = &pbuf[ni & 1][0];
    {
      float xr[2], rsum[2], rsq[2];
#pragma unroll
      for (int rt = 0; rt < 2; ++rt) {
        xr[rt] = xs[rt * 16 + cl][ni];
        rsum[rt] = 0.f;
        rsq[rt] = 0.f;
      }
#pragma unroll
      for (int ct = 0; ct < 2; ++ct) {
        const int cl4 = (w * 2 + ct) * 16 + g * 4;
        f32x4 f2b4 = *reinterpret_cast<const f32x4*>(pb + 0 * 256 + cl4);
        f32x4 sw4  = *reinterpret_cast<const f32x4*>(pb + 1 * 256 + cl4);
        f32x4 sb4  = *reinterpret_cast<const f32x4*>(pb + 2 * 256 + cl4);
        f32x4 gw4  = *reinterpret_cast<const f32x4*>(pb + 3 * 256 + cl4);
        f32x4 gb4  = *reinterpret_cast<const f32x4*>(pb + 4 * 256 + cl4);
#pragma unroll
        for (int rt = 0; rt < 2; ++rt) {
#pragma unroll
          for (int j = 0; j < 4; ++j) {
            float hv = acc[ct][rt][j] + f2b4[j];
            float sk = fmaf(xr[rt], sw4[j], sb4[j]);
            float gv = __fdividef(1.f, 1.f + __expf(-fmaf(xr[rt], gw4[j], gb4[j])));
            float p = fmaf(gv, hv - sk, sk);
            acc[ct][rt][j] = p;
            rsum[rt] += p;
            rsq[rt] = fmaf(p, p, rsq[rt]);
          }
        }
      }
#pragma unroll
      for (int rt = 0; rt < 2; ++rt) {
        rsum[rt] += __shfl_xor(rsum[rt], 16);
        rsum[rt] += __shfl_xor(rsum[rt], 32);
        rsq[rt]  += __shfl_xor(rsq[rt], 16);
        rsq[rt]  += __shfl_xor(rsq[rt], 32);
      }
      if (g == 0) {
#pragma unroll
        for (int rt = 0; rt < 2; ++rt) {
          atomicAdd(&sums[par][rt * 16 + cl][0], rsum[rt]);
          atomicAdd(&sums[par][rt * 16 + cl][1], rsq[rt]);
        }
      }
    }
    if (t < 64) (&sums[par ^ 1][0][0])[t] = 0.f;  // zero parity for ni+1
    __syncthreads();   // B2: sums ready; param stage for ni+1 drained

    // ---- pass 2: normalize + softmax-weighted accumulate (registers) ----
    {
      float rsv[2], mrs[2], svv[2];
#pragma unroll
      for (int rt = 0; rt < 2; ++rt) {
        int row = rt * 16 + cl;
        float s0 = sums[par][row][0], s1 = sums[par][row][1];
        float mu = s0 * (1.f / 256.f);
        float rs = rsqrtf(fmaxf(s1 * (1.f / 256.f) - mu * mu, 0.f) + 1e-5f);
        rsv[rt] = rs;
        mrs[rt] = -mu * rs;
        svv[rt] = ss[row][ni];
      }
#pragma unroll
      for (int ct = 0; ct < 2; ++ct) {
        const int cl4 = (w * 2 + ct) * 16 + g * 4;
        f32x4 lg4 = *reinterpret_cast<const f32x4*>(pb + 5 * 256 + cl4);
        f32x4 lb4 = *reinterpret_cast<const f32x4*>(pb + 6 * 256 + cl4);
#pragma unroll
        for (int rt = 0; rt < 2; ++rt) {
#pragma unroll
          for (int j = 0; j < 4; ++j) {
            float tnorm = fmaf(acc[ct][rt][j], rsv[rt], mrs[rt]);
            float emb = fmaf(tnorm, lg4[j], lb4[j]);
            comb_acc[ct][rt][j] = fmaf(svv[rt], emb, comb_acc[ct][rt][j]);
          }
        }
      }
    }
  }
#undef BFRAG

  float* outp;
  if (ATOMIC) outp = comb;
  else outp = (nch == 0) ? comb : slabs + (size_t)(nch - 1) * SLAB_FLOATS;
#pragma unroll
  for (int ct = 0; ct < 2; ++ct)
#pragma unroll
    for (int rt = 0; rt < 2; ++rt) {
      size_t idx = (size_t)(b0 + rt * 16 + cl) * 256 + (w * 2 + ct) * 16 + g * 4;
      if (ATOMIC) {
#pragma unroll
        for (int j = 0; j < 4; ++j)
          atomicAdd(&outp[idx + j], comb_acc[ct][rt][j]);
      } else {
        *reinterpret_cast<f32x4*>(outp + idx) = comb_acc[ct][rt];
      }
    }
}

// ---------------------------------------------------------------------------
// k3: comb += sum of the 7 partial slabs.  grid 1024 x 256, f32x4 per thread.
// ---------------------------------------------------------------------------
__global__ __launch_bounds__(256) void k3_reduce(float* __restrict__ comb,
                                                 const float* __restrict__ slabs) {
  size_t i = (size_t)blockIdx.x * 256 + threadIdx.x;   // f32x4 index
  f32x4 v = reinterpret_cast<const f32x4*>(comb)[i];
#pragma unroll
  for (int s = 0; s < 7; ++s)
    v += reinterpret_cast<const f32x4*>(slabs)[s * (SLAB_FLOATS / 4) + i];
  reinterpret_cast<f32x4*>(comb)[i] = v;
}

// ---------------------------------------------------------------------------
extern "C" void kernel_launch(void* const* d_in, const int* in_sizes, int n_in,
                              void* d_out, int out_size, void* d_ws, size_t ws_size,
                              hipStream_t stream) {
  const float* x   = (const float*)d_in[0];
  const float* f1w = (const float*)d_in[1];
  const float* f1b = (const float*)d_in[2];
  const float* f2w = (const float*)d_in[3];
  const float* f2b = (const float*)d_in[4];
  const float* fsw = (const float*)d_in[5];
  const float* fsb = (const float*)d_in[6];
  const float* fgw = (const float*)d_in[7];
  const float* fgb = (const float*)d_in[8];
  const float* flg = (const float*)d_in[9];
  const float* flb = (const float*)d_in[10];
  const float* g1w = (const float*)d_in[11];
  const float* g1b = (const float*)d_in[12];
  const float* g2w = (const float*)d_in[13];
  const float* g2b = (const float*)d_in[14];
  const float* gsw = (const float*)d_in[15];
  const float* gsb = (const float*)d_in[16];
  const float* ggw = (const float*)d_in[17];
  const float* ggb = (const float*)d_in[18];
  const float* glg = (const float*)d_in[19];
  const float* glb = (const float*)d_in[20];

  float* out  = (float*)d_out;
  float* comb = out;                          // (4096,256)
  float* spw  = out + (size_t)4096 * 256;     // (4096,64)
  ushort* w2p = (ushort*)d_ws;                // 8.4 MB packed bf16 W-frags
  float* slabs = (float*)((char*)d_ws + W2P_BYTES);  // 7 x 4 MB partials

  k0_pack<<<512, 256, 0, stream>>>(g2w, w2p);
  k1_select<<<512, 256, 0, stream>>>(x, f1w, f1b, f2w, f2b, fsw, fsb,
                                     fgw, fgb, flg, flb, spw);
  if (ws_size >= WS_NEEDED) {
    k2_main<false><<<1024, 512, 0, stream>>>(x, w2p, g1w, g1b, g2b, gsw, gsb,
                                             ggw, ggb, glg, glb, spw, comb, slabs);
    k3_reduce<<<1024, 256, 0, stream>>>(comb, slabs);
  } else {
    hipMemsetAsync(comb, 0, (size_t)4096 * 256 * sizeof(float), stream);
    k2_main<true><<<1024, 512, 0, stream>>>(x, w2p, g1w, g1b, g2b, gsw, gsb,
                                            ggw, ggb, glg, glb, spw, comb, slabs);
  }
}

// Round 12
// 129.586 us; speedup vs baseline: 1.3470x; 1.0529x over previous
//
#include <hip/hip_runtime.h>
#include <hip/hip_bf16.h>

typedef __attribute__((ext_vector_type(4))) float f32x4;
typedef __attribute__((ext_vector_type(8))) short s16x8;

#define W2P_BYTES   8388608ull                 // 64*256*256 bf16
#define SLAB_FLOATS 1048576ull                 // 4096*256
#define WS_NEEDED   (W2P_BYTES + 7ull * SLAB_FLOATS * 4ull)

// ---------------------------------------------------------------------------
// k01: fused weight-pack (blocks 0..511) + f-path select (blocks 512..1023).
// Disjoint block ranges, shared LDS buffer, zero interaction.
// pack: g_fc2_w (64,256,256) fp32 -> bf16 MFMA fragments, 1KB contiguous per
// fragment; frag f = (n*8+ks)*16 + ct: lane l, elem j =
//   g2w[n][ks*32 + (l>>4)*8 + j][ct*16 + (l&15)]
// select: sparse_w (4096,64), 8 rows per block.
// ---------------------------------------------------------------------------
__global__ __launch_bounds__(256) void k01(
    const float* __restrict__ g2w, ushort* __restrict__ out,
    const float* __restrict__ x,
    const float* __restrict__ w1, const float* __restrict__ b1,
    const float* __restrict__ w2, const float* __restrict__ b2,
    const float* __restrict__ wsk, const float* __restrict__ bsk,
    const float* __restrict__ wg, const float* __restrict__ bg,
    const float* __restrict__ lng, const float* __restrict__ lnb,
    float* __restrict__ spw) {
  __shared__ __align__(16) float shbuf[32 * 257];
  const int t = threadIdx.x;
  if (blockIdx.x < 512) {
    // ---------------- pack path ----------------
    float (*tile)[257] = reinterpret_cast<float (*)[257]>(shbuf);
    const int n = blockIdx.x >> 3, ks = blockIdx.x & 7;
    const float* src = g2w + ((size_t)n * 256 + ks * 32) * 256;
    for (int i = t; i < 8192; i += 256)
      tile[i >> 8][i & 255] = src[i];
    __syncthreads();
#pragma unroll
    for (int q = 0; q < 4; ++q) {
      int chunk = q * 256 + t;
      int ct = chunk >> 6, l = chunk & 63;
      int g = l >> 4, cl = l & 15;
      s16x8 pk;
#pragma unroll
      for (int j = 0; j < 8; ++j) {
        __hip_bfloat16 h = __float2bfloat16(tile[g * 8 + j][ct * 16 + cl]);
        pk[j] = *reinterpret_cast<short*>(&h);
      }
      *reinterpret_cast<s16x8*>(out + ((size_t)(n * 8 + ks) * 1024 + chunk) * 8) = pk;
    }
  } else {
    // ---------------- select path ----------------
    float (*xs)[64]  = reinterpret_cast<float (*)[64]>(shbuf);
    float (*t1)[256] = reinterpret_cast<float (*)[256]>(shbuf + 512);
    float (*wvv)[64] = reinterpret_cast<float (*)[64]>(shbuf + 2560);
    const int b0 = (int)(blockIdx.x - 512) * 8;
    if (t < 128) {
      const f32x4* xin = reinterpret_cast<const f32x4*>(x + (size_t)b0 * 64);
      reinterpret_cast<f32x4*>(&xs[0][0])[t] = xin[t];
    }
    __syncthreads();
    {  // t1[r][h] = elu(x @ f_fc1_w + b1), thread t = h
      float acc[8];
      float bias = b1[t];
#pragma unroll
      for (int r = 0; r < 8; ++r) acc[r] = bias;
      for (int n = 0; n < 64; ++n) {
        float w = w1[n * 256 + t];
#pragma unroll
        for (int r = 0; r < 8; ++r) acc[r] = fmaf(xs[r][n], w, acc[r]);
      }
#pragma unroll
      for (int r = 0; r < 8; ++r) {
        float z = acc[r];
        t1[r][t] = fmaxf(z, 0.f) + (__expf(fminf(z, 0.f)) - 1.f);
      }
    }
    __syncthreads();
    {  // h2 / skip / gate, thread = (nn = t&63, rg = t>>6), rows rg, rg+4
      const int nn = t & 63, rg = t >> 6;
      float a2[2], as_[2], ag[2];
      float bb2 = b2[nn], bbs = bsk[nn], bbg = bg[nn];
#pragma unroll
      for (int i = 0; i < 2; ++i) { a2[i] = bb2; as_[i] = bbs; ag[i] = bbg; }
      for (int h = 0; h < 256; ++h) {
        float w = w2[h * 64 + nn];
#pragma unroll
        for (int i = 0; i < 2; ++i) a2[i] = fmaf(t1[rg + 4 * i][h], w, a2[i]);
      }
      for (int m = 0; m < 64; ++m) {
        float ws_ = wsk[m * 64 + nn], wg_ = wg[m * 64 + nn];
#pragma unroll
        for (int i = 0; i < 2; ++i) {
          float xv = xs[rg + 4 * i][m];
          as_[i] = fmaf(xv, ws_, as_[i]);
          ag[i]  = fmaf(xv, wg_, ag[i]);
        }
      }
#pragma unroll
      for (int i = 0; i < 2; ++i) {
        float gt = __fdividef(1.f, 1.f + __expf(-ag[i]));
        wvv[rg + 4 * i][nn] = fmaf(gt, a2[i] - as_[i], as_[i]);
      }
    }
    __syncthreads();
    {  // LN over 64 + softmax over 64, wave handles 2 rows
      const int lane = t & 63, wid = t >> 6;
      float gl = lng[lane], bl = lnb[lane];
#pragma unroll
      for (int rr = 0; rr < 2; ++rr) {
        int r = wid * 2 + rr;
        float v = wvv[r][lane];
        float s = v;
        for (int m = 1; m < 64; m <<= 1) s += __shfl_xor(s, m);
        float mu = s * (1.f / 64.f);
        float d = v - mu;
        float q = d * d;
        for (int m = 1; m < 64; m <<= 1) q += __shfl_xor(q, m);
        float wn = d * rsqrtf(q * (1.f / 64.f) + 1e-5f) * gl + bl;
        float mx = wn;
        for (int m = 1; m < 64; m <<= 1) mx = fmaxf(mx, __shfl_xor(mx, m));
        float e = __expf(wn - mx);
        float se = e;
        for (int m = 1; m < 64; m <<= 1) se += __shfl_xor(se, m);
        spw[(size_t)(b0 + r) * 64 + lane] = __fdividef(e, se);
      }
    }
  }
}

// ---------------------------------------------------------------------------
// k2: fused einsum + gate/skip + LN(H) + weighted accumulate.
// ONE barrier per ni (R11 schedule + the missing PROLOGUE barrier fixed:
// AGEN(n0) must run AFTER the xs/ss stores are barrier-visible).
// Iteration: [zero sums ring -> issue W(ks0,1) -> pass2(ni-1) ->
//   stage params(n+1) -> ks-loop -> ep1+LDS atomics -> A-gen(ni+1) -> barrier]
// Ab double-buffered; pbuf/sums 3-rings (every slot write >=1 barrier after
// its last reader).  Only acc+comb_acc live across the barrier; W prefetch
// depth-2 within-n (R9's spill cause avoided).
// grid 1024: bid = btile*8 + nchunk; 512 thr / 8 waves; 2 blocks/CU; no tail.
// ---------------------------------------------------------------------------
template <bool ATOMIC>
__global__ __launch_bounds__(512, 4) void k2_main(
    const float* __restrict__ x,
    const ushort* __restrict__ w2p,
    const float* __restrict__ fc1w, const float* __restrict__ fc1b,
    const float* __restrict__ fc2b,
    const float* __restrict__ skw, const float* __restrict__ skb,
    const float* __restrict__ gww, const float* __restrict__ gwb,
    const float* __restrict__ lng, const float* __restrict__ lnb,
    const float* __restrict__ spw,
    float* __restrict__ comb, float* __restrict__ slabs) {
  __shared__ __align__(16) char Ab[2][16384];   // act tiles 32x256 bf16, swizzled
  __shared__ __align__(16) float pbuf[3][1792]; // 7 param rows x 256, 3-ring
  __shared__ float xs[32][9];
  __shared__ float ss[32][9];
  __shared__ float sums[3][32][2];              // 3-ring

  const int bid = blockIdx.x;
  const int nch = bid & 7;
  const int b0  = (bid >> 3) * 32;
  const int t = threadIdx.x;
  const int lane = t & 63;
  const int w = t >> 6;          // 0..7 (32-col band)
  const int g = lane >> 4;
  const int cl = lane & 15;
  const int n0 = nch * 8;

  if (t < 256) {
    int r = t >> 3, j = t & 7;
    xs[r][j] = x[(size_t)(b0 + r) * 64 + nch * 8 + j];
    ss[r][j] = spw[(size_t)(b0 + r) * 64 + nch * 8 + j];
  }
  if (t < 64) (&sums[0][0][0])[t] = 0.f;   // slot 0 for ni=0

  // stage params(nn) -> pbuf[buf]: wave w<7 stages its array, 1 inst/wave
  auto STAGE = [&](int nn, int buf) {
    if (w < 7) {
      const float* ps;
      switch (w) {
        case 0: ps = fc2b; break;
        case 1: ps = skw;  break;
        case 2: ps = skb;  break;
        case 3: ps = gww;  break;
        case 4: ps = gwb;  break;
        case 5: ps = lng;  break;
        default: ps = lnb; break;
      }
      __builtin_amdgcn_global_load_lds(
          (const __attribute__((address_space(1))) unsigned int*)(ps + nn * 256 + lane * 4),
          (__attribute__((address_space(3))) unsigned int*)&pbuf[buf][w * 256],
          16, 0, 0);
    }
  };

  // A-gen: act[r][k] = elu(x[b0+r][nn]*fc1w[nn][k] + fc1b[nn][k]) -> abuf
  auto AGEN = [&](int nn, char* abuf) {
    const int kc = t & 31;
    const int rb = t >> 5;       // 0..15
    const int nloc = nn - n0;
    const float* w1p = fc1w + nn * 256 + kc * 8;
    const float* b1p = fc1b + nn * 256 + kc * 8;
    f32x4 wlo = *reinterpret_cast<const f32x4*>(w1p);
    f32x4 whi = *reinterpret_cast<const f32x4*>(w1p + 4);
    f32x4 blo = *reinterpret_cast<const f32x4*>(b1p);
    f32x4 bhi = *reinterpret_cast<const f32x4*>(b1p + 4);
#pragma unroll
    for (int i = 0; i < 2; ++i) {
      int r = rb + 16 * i;
      float xv = xs[r][nloc];
      s16x8 pk;
#pragma unroll
      for (int j = 0; j < 4; ++j) {
        float z0 = fmaf(xv, wlo[j], blo[j]);
        float z1 = fmaf(xv, whi[j], bhi[j]);
        float e0 = fmaxf(z0, 0.f) + (__expf(fminf(z0, 0.f)) - 1.f);
        float e1 = fmaxf(z1, 0.f) + (__expf(fminf(z1, 0.f)) - 1.f);
        __hip_bfloat16 h0 = __float2bfloat16(e0);
        __hip_bfloat16 h1 = __float2bfloat16(e1);
        pk[j]     = *reinterpret_cast<short*>(&h0);
        pk[j + 4] = *reinterpret_cast<short*>(&h1);
      }
      *reinterpret_cast<s16x8*>(abuf + r * 512 + ((kc << 4) ^ ((r & 7) << 4))) = pk;
    }
  };

  f32x4 comb_acc[2][2];
  f32x4 acc[2][2];               // live across the barrier into pass2
#pragma unroll
  for (int a = 0; a < 2; ++a)
#pragma unroll
    for (int b = 0; b < 2; ++b) comb_acc[a][b] = (f32x4){0.f, 0.f, 0.f, 0.f};

  // pass2 for n index pni: normalize + softmax-weighted accumulate
  auto PASS2 = [&](int pni) {
    const float* sb = &sums[pni % 3][0][0];
    const float* pb = &pbuf[pni % 3][0];
    float rsv[2], mrs[2], svv[2];
#pragma unroll
    for (int rt = 0; rt < 2; ++rt) {
      int row = rt * 16 + cl;
      float s0 = sb[row * 2], s1 = sb[row * 2 + 1];
      float mu = s0 * (1.f / 256.f);
      float rs = rsqrtf(fmaxf(s1 * (1.f / 256.f) - mu * mu, 0.f) + 1e-5f);
      rsv[rt] = rs;
      mrs[rt] = -mu * rs;
      svv[rt] = ss[row][pni];
    }
#pragma unroll
    for (int ct = 0; ct < 2; ++ct) {
      const int cl4 = (w * 2 + ct) * 16 + g * 4;
      f32x4 lg4 = *reinterpret_cast<const f32x4*>(pb + 5 * 256 + cl4);
      f32x4 lb4 = *reinterpret_cast<const f32x4*>(pb + 6 * 256 + cl4);
#pragma unroll
      for (int rt = 0; rt < 2; ++rt) {
#pragma unroll
        for (int j = 0; j < 4; ++j) {
          float tnorm = fmaf(acc[ct][rt][j], rsv[rt], mrs[rt]);
          float emb = fmaf(tnorm, lg4[j], lb4[j]);
          comb_acc[ct][rt][j] = fmaf(svv[rt], emb, comb_acc[ct][rt][j]);
        }
      }
    }
  };

  const s16x8* wf = reinterpret_cast<const s16x8*>(w2p);
#define BFRAG(nn, kk, ct) \
  (wf + (((size_t)((nn) * 8 + (kk)) * 16 + w * 2 + (ct)) * 64 + lane))

  __syncthreads();               // xs/ss (and sums slot 0) visible to ALL waves
  STAGE(n0, 0);                  // params(n0); drained by the barrier below
  AGEN(n0, Ab[0]);               // reads xs -- now safe
  __syncthreads();               // Ab[0] ready; DMA drained

  for (int ni = 0; ni < 8; ++ni) {
    const int n = n0 + ni;
    // 1. rotate-zero sums slot for ni+1 (last read: pass2(ni-2), >=1 barrier ago)
    if (t < 64) (&sums[(ni + 1) % 3][0][0])[t] = 0.f;

    // 2. issue W prefetch ks=0,1 (latency covered by pass2 + stage below)
    s16x8 bfa[2], bfb[2];
#pragma unroll
    for (int ct = 0; ct < 2; ++ct) {
      bfa[ct] = *BFRAG(n, 0, ct);
      bfb[ct] = *BFRAG(n, 1, ct);
    }

    // 3. pass2 for previous n (reads sums/pbuf slot (ni-1)%3 + held acc)
    if (ni > 0) PASS2(ni - 1);

    // 4. stage params(n+1) into slot (ni+1)%3 (last read: ep1/pass2(ni-2))
    if (ni < 7) STAGE(n + 1, (ni + 1) % 3);

    // 5. K-loop: 8 ks, MFMA from Ab[ni&1] x W, rolling depth-2 prefetch
#pragma unroll
    for (int a = 0; a < 2; ++a)
#pragma unroll
      for (int b = 0; b < 2; ++b) acc[a][b] = (f32x4){0.f, 0.f, 0.f, 0.f};

    const char* abase = Ab[ni & 1];
#pragma unroll
    for (int ks = 0; ks < 8; ++ks) {
      s16x8* cur = (ks & 1) ? bfb : bfa;
      s16x8 af[2];
#pragma unroll
      for (int rt = 0; rt < 2; ++rt) {
        int row = rt * 16 + cl;
        af[rt] = *reinterpret_cast<const s16x8*>(
            abase + row * 512 + (((ks * 4 + g) << 4) ^ ((row & 7) << 4)));
      }
#pragma unroll
      for (int ct = 0; ct < 2; ++ct)
#pragma unroll
        for (int rt = 0; rt < 2; ++rt)
          acc[ct][rt] = __builtin_amdgcn_mfma_f32_16x16x32_bf16(
              cur[ct], af[rt], acc[ct][rt], 0, 0, 0);
      if (ks < 6) {
#pragma unroll
        for (int ct = 0; ct < 2; ++ct) cur[ct] = *BFRAG(n, ks + 2, ct);
      }
    }

    // 6. ep1: gate mix + lane-local row stats -> sums[ni%3]
    {
      const float* pb = &pbuf[ni % 3][0];
      float xr[2], rsum[2], rsq[2];
#pragma unroll
      for (int rt = 0; rt < 2; ++rt) {
        xr[rt] = xs[rt * 16 + cl][ni];
        rsum[rt] = 0.f;
        rsq[rt] = 0.f;
      }
#pragma unroll
      for (int ct = 0; ct < 2; ++ct) {
        const int cl4 = (w * 2 + ct) * 16 + g * 4;
        f32x4 f2b4 = *reinterpret_cast<const f32x4*>(pb + 0 * 256 + cl4);
        f32x4 sw4  = *reinterpret_cast<const f32x4*>(pb + 1 * 256 + cl4);
        f32x4 sb4  = *reinterpret_cast<const f32x4*>(pb + 2 * 256 + cl4);
        f32x4 gw4  = *reinterpret_cast<const f32x4*>(pb + 3 * 256 + cl4);
        f32x4 gb4  = *reinterpret_cast<const f32x4*>(pb + 4 * 256 + cl4);
#pragma unroll
        for (int rt = 0; rt < 2; ++rt) {
#pragma unroll
          for (int j = 0; j < 4; ++j) {
            float hv = acc[ct][rt][j] + f2b4[j];
            float sk = fmaf(xr[rt], sw4[j], sb4[j]);
            float gv = __fdividef(1.f, 1.f + __expf(-fmaf(xr[rt], gw4[j], gb4[j])));
            float p = fmaf(gv, hv - sk, sk);
            acc[ct][rt][j] = p;
            rsum[rt] += p;
            rsq[rt] = fmaf(p, p, rsq[rt]);
          }
        }
      }
#pragma unroll
      for (int rt = 0; rt < 2; ++rt) {
        rsum[rt] += __shfl_xor(rsum[rt], 16);
        rsum[rt] += __shfl_xor(rsum[rt], 32);
        rsq[rt]  += __shfl_xor(rsq[rt], 16);
        rsq[rt]  += __shfl_xor(rsq[rt], 32);
      }
      if (g == 0) {
        float* sb2 = &sums[ni % 3][0][0];
#pragma unroll
        for (int rt = 0; rt < 2; ++rt) {
          atomicAdd(&sb2[(rt * 16 + cl) * 2 + 0], rsum[rt]);
          atomicAdd(&sb2[(rt * 16 + cl) * 2 + 1], rsq[rt]);
        }
      }
    }

    // 7. A-gen(ni+1) into the other Ab buffer (drains the atomics)
    if (ni < 7) AGEN(n + 1, Ab[(ni + 1) & 1]);

    // 8. the ONLY barrier of the iteration
    __syncthreads();
  }

  PASS2(7);
#undef BFRAG

  float* outp;
  if (ATOMIC) outp = comb;
  else outp = (nch == 0) ? comb : slabs + (size_t)(nch - 1) * SLAB_FLOATS;
#pragma unroll
  for (int ct = 0; ct < 2; ++ct)
#pragma unroll
    for (int rt = 0; rt < 2; ++rt) {
      size_t idx = (size_t)(b0 + rt * 16 + cl) * 256 + (w * 2 + ct) * 16 + g * 4;
      if (ATOMIC) {
#pragma unroll
        for (int j = 0; j < 4; ++j)
          atomicAdd(&outp[idx + j], comb_acc[ct][rt][j]);
      } else {
        *reinterpret_cast<f32x4*>(outp + idx) = comb_acc[ct][rt];
      }
    }
}

// ---------------------------------------------------------------------------
// k3: comb += sum of the 7 partial slabs.  grid 1024 x 256, f32x4 per thread.
// ---------------------------------------------------------------------------
__global__ __launch_bounds__(256) void k3_reduce(float* __restrict__ comb,
                                                 const float* __restrict__ slabs) {
  size_t i = (size_t)blockIdx.x * 256 + threadIdx.x;   // f32x4 index
  f32x4 v = reinterpret_cast<const f32x4*>(comb)[i];
#pragma unroll
  for (int s = 0; s < 7; ++s)
    v += reinterpret_cast<const f32x4*>(slabs)[s * (SLAB_FLOATS / 4) + i];
  reinterpret_cast<f32x4*>(comb)[i] = v;
}

// ---------------------------------------------------------------------------
extern "C" void kernel_launch(void* const* d_in, const int* in_sizes, int n_in,
                              void* d_out, int out_size, void* d_ws, size_t ws_size,
                              hipStream_t stream) {
  const float* x   = (const float*)d_in[0];
  const float* f1w = (const float*)d_in[1];
  const float* f1b = (const float*)d_in[2];
  const float* f2w = (const float*)d_in[3];
  const float* f2b = (const float*)d_in[4];
  const float* fsw = (const float*)d_in[5];
  const float* fsb = (const float*)d_in[6];
  const float* fgw = (const float*)d_in[7];
  const float* fgb = (const float*)d_in[8];
  const float* flg = (const float*)d_in[9];
  const float* flb = (const float*)d_in[10];
  const float* g1w = (const float*)d_in[11];
  const float* g1b = (const float*)d_in[12];
  const float* g2w = (const float*)d_in[13];
  const float* g2b = (const float*)d_in[14];
  const float* gsw = (const float*)d_in[15];
  const float* gsb = (const float*)d_in[16];
  const float* ggw = (const float*)d_in[17];
  const float* ggb = (const float*)d_in[18];
  const float* glg = (const float*)d_in[19];
  const float* glb = (const float*)d_in[20];

  float* out  = (float*)d_out;
  float* comb = out;                          // (4096,256)
  float* spw  = out + (size_t)4096 * 256;     // (4096,64)
  ushort* w2p = (ushort*)d_ws;                // 8.4 MB packed bf16 W-frags
  float* slabs = (float*)((char*)d_ws + W2P_BYTES);  // 7 x 4 MB partials

  k01<<<1024, 256, 0, stream>>>(g2w, w2p, x, f1w, f1b, f2w, f2b,
                                fsw, fsb, fgw, fgb, flg, flb, spw);
  if (ws_size >= WS_NEEDED) {
    k2_main<false><<<1024, 512, 0, stream>>>(x, w2p, g1w, g1b, g2b, gsw, gsb,
                                             ggw, ggb, glg, glb, spw, comb, slabs);
    k3_reduce<<<1024, 256, 0, stream>>>(comb, slabs);
  } else {
    hipMemsetAsync(comb, 0, (size_t)4096 * 256 * sizeof(float), stream);
    k2_main<true><<<1024, 512, 0, stream>>>(x, w2p, g1w, g1b, g2b, gsw, gsb,
                                            ggw, ggb, glg, glb, spw, comb, slabs);
  }
}